// Round 3
// baseline (332.010 us; speedup 1.0000x reference)
//
#include <hip/hip_runtime.h>
#include <stdint.h>

#define HT_STRIDE 262144   // 4096*64 elements per head

typedef __attribute__((ext_vector_type(8))) short bf16x8;
typedef __attribute__((ext_vector_type(4))) float f32x4;

__device__ __forceinline__ unsigned short f2bf(float f) {
    unsigned int u = __float_as_uint(f);
    u += 0x7FFFu + ((u >> 16) & 1u);
    return (unsigned short)(u >> 16);
}

// ---------------------------------------------------------------------------
// Kernel A: ht = h(4096x128) @ W(128x512), f32 in, f32 out.
// Flat result == ht (1,8,4096,64) layout (reshape is flat-preserving).
// Written into d_out (ht is exactly out's size; k_attn overwrites it last).
// 512 blocks x 256 threads, 8 rows per block, 2 adjacent cols per thread.
// ---------------------------------------------------------------------------
__global__ void __launch_bounds__(256) k_linear(const float* __restrict__ h,
                                                const float* __restrict__ W,
                                                float* __restrict__ ht) {
    __shared__ float hs[8][128];
    const int t = threadIdx.x;
    const int n0 = blockIdx.x * 8;
    {
        float4 v = ((const float4*)(h + n0 * 128))[t];   // 256 float4 = 8 rows x 128
        int e = t * 4;
        int r = e >> 7, f = e & 127;
        hs[r][f + 0] = v.x; hs[r][f + 1] = v.y;
        hs[r][f + 2] = v.z; hs[r][f + 3] = v.w;
    }
    __syncthreads();
    float acc0[8], acc1[8];
    #pragma unroll
    for (int r = 0; r < 8; ++r) { acc0[r] = 0.f; acc1[r] = 0.f; }
    const float2* Wf = (const float2*)W;     // row f = 256 float2 (512 cols)
    for (int f = 0; f < 128; ++f) {
        float2 wp = Wf[f * 256 + t];         // cols 2t, 2t+1
        #pragma unroll
        for (int r = 0; r < 8; ++r) {
            float hv = hs[r][f];
            acc0[r] = fmaf(hv, wp.x, acc0[r]);
            acc1[r] = fmaf(hv, wp.y, acc1[r]);
        }
    }
    float2* ob = (float2*)ht;
    #pragma unroll
    for (int r = 0; r < 8; ++r) {
        ob[(n0 + r) * 256 + t] = make_float2(acc0[r], acc1[r]);
    }
}

// ---------------------------------------------------------------------------
// Kernel A2: htT[hd][o][m] = bf16(ht[hd][m][o])  (o-major, MFMA A operand)
// ---------------------------------------------------------------------------
__global__ void __launch_bounds__(256) k_transpose(const float* __restrict__ ht,
                                                   unsigned short* __restrict__ htT) {
    __shared__ unsigned short tile[64][65];
    const int t = threadIdx.x;
    const int hd = blockIdx.x >> 6;
    const int m0 = (blockIdx.x & 63) * 64;
    const float* s = ht + hd * HT_STRIDE + m0 * 64;
    #pragma unroll
    for (int i = 0; i < 16; ++i) {
        int idx = t + 256 * i;
        tile[idx >> 6][idx & 63] = f2bf(s[idx]);
    }
    __syncthreads();
    unsigned short* d = htT + hd * HT_STRIDE + m0;
    #pragma unroll
    for (int i = 0; i < 16; ++i) {
        int idx = t + 256 * i;
        d[(idx >> 6) * 4096 + (idx & 63)] = tile[idx & 63][idx >> 6];
    }
}

// ---------------------------------------------------------------------------
// Kernel B: src[p] = <ht[p,:], a[hd,0:64]>, tgt[p] = <ht[p,:], a[hd,64:128]>
// one wave per (head,node) pair p.
// ---------------------------------------------------------------------------
__global__ void __launch_bounds__(256) k_srctgt(const float* __restrict__ ht,
                                                const float* __restrict__ aW,
                                                float* __restrict__ src,
                                                float* __restrict__ tgt) {
    const int t = threadIdx.x;
    const int p = blockIdx.x * 4 + (t >> 6);   // head*4096 + m
    const int lane = t & 63;
    const int hd = p >> 12;
    float hv = ht[p * 64 + lane];
    float a1 = aW[hd * 128 + lane];
    float a2 = aW[hd * 128 + 64 + lane];
    float s = hv * a1, g = hv * a2;
    #pragma unroll
    for (int off = 32; off > 0; off >>= 1) {
        s += __shfl_down(s, off, 64);
        g += __shfl_down(g, off, 64);
    }
    if (lane == 0) { src[p] = s; tgt[p] = g; }
}

// ---------------------------------------------------------------------------
// Kernel C: tmax[hd] = max_m tgt[hd][m]
// ---------------------------------------------------------------------------
__global__ void __launch_bounds__(256) k_tgtmax(const float* __restrict__ tgt,
                                                float* __restrict__ tmax) {
    __shared__ float red[256];
    const int t = threadIdx.x;
    const int hd = blockIdx.x;
    float m = -1e30f;
    for (int i = t; i < 4096; i += 256) m = fmaxf(m, tgt[hd * 4096 + i]);
    red[t] = m;
    __syncthreads();
    for (int s2 = 128; s2 > 0; s2 >>= 1) {
        if (t < s2) red[t] = fmaxf(red[t], red[t + s2]);
        __syncthreads();
    }
    if (t == 0) tmax[hd] = red[0];
}

// ---------------------------------------------------------------------------
// Kernel D: fused GAT attention row-block (flash-style, single pass).
// block = 512 threads = 8 waves (one head each), 16 rows shared adj stripe.
// Safe row max: mi = lrelu(src_i + max_j tgt_j) >= every e_ij (lrelu monotone),
// so exp(e - mi) <= 1 and no online rescale is needed. No barriers in loop.
// Oᵀ via MFMA: P is the B operand (lane = row i=lane&15, k=quad*8+j), A-frags
// are contiguous uint4 from bf16 htT. Weights f32; bf16 only for the MFMA.
// ---------------------------------------------------------------------------
__global__ void __launch_bounds__(512) k_attn(const int* __restrict__ adj,
                                              const unsigned short* __restrict__ htT,
                                              const float* __restrict__ src,
                                              const float* __restrict__ tgt,
                                              const float* __restrict__ tmax,
                                              float* __restrict__ out) {
    const int t = threadIdx.x;
    const int head = t >> 6;
    const int lane = t & 63;
    const int li = lane & 15;
    const int quad = lane >> 4;
    const int i0 = blockIdx.x * 16;

    const float sv = src[head * 4096 + i0 + li];
    const float tm0 = sv + tmax[head];
    const float mi = fmaxf(tm0, 0.2f * tm0);   // lrelu(src+max tgt) >= true row max

    f32x4 acc[4];
    #pragma unroll
    for (int f = 0; f < 4; ++f) acc[f] = (f32x4){0.f, 0.f, 0.f, 0.f};
    float pd = 0.f;

    const int4*   adjp = (const int4*)(adj + (i0 + li) * 4096);
    const float4* tgtp = (const float4*)(tgt + head * 4096);
    const uint4*  ap   = (const uint4*)(htT + head * HT_STRIDE);

    for (int c = 0; c < 128; ++c) {
        const int kb = c * 32 + quad * 8;      // this lane's 8 j's
        int4   ad0 = adjp[(kb >> 2) + 0];
        int4   ad1 = adjp[(kb >> 2) + 1];
        float4 tg0 = tgtp[(kb >> 2) + 0];
        float4 tg1 = tgtp[(kb >> 2) + 1];
        const float tt[8] = {tg0.x, tg0.y, tg0.z, tg0.w, tg1.x, tg1.y, tg1.z, tg1.w};
        const int   aa[8] = {ad0.x, ad0.y, ad0.z, ad0.w, ad1.x, ad1.y, ad1.z, ad1.w};
        bf16x8 bfrag;
        #pragma unroll
        for (int j = 0; j < 8; ++j) {
            float e = sv + tt[j];
            e = fmaxf(e, 0.2f * e);            // leaky relu
            float wv = (aa[j] > 0) ? __expf(e - mi) : 0.f;
            pd += wv;
            bfrag[j] = (short)f2bf(wv);
        }
        #pragma unroll
        for (int f = 0; f < 4; ++f) {
            const uint4 av = ap[(((f * 16 + li) * 4096 + kb) >> 3)];
            bf16x8 afrag = __builtin_bit_cast(bf16x8, av);
            acc[f] = __builtin_amdgcn_mfma_f32_16x16x32_bf16(afrag, bfrag, acc[f], 0, 0, 0);
        }
    }

    // denominator: sum over the 4 quads (lane bits 4,5)
    pd += __shfl_xor(pd, 16, 64);
    pd += __shfl_xor(pd, 32, 64);
    const float rd = 1.0f / pd;

    // D: col = lane&15 = i, row = quad*4+reg = o_local (within f*16 group)
    float4* op = (float4*)(out + head * HT_STRIDE + (i0 + li) * 64);
    #pragma unroll
    for (int f = 0; f < 4; ++f) {
        float4 v = make_float4(acc[f][0] * rd, acc[f][1] * rd,
                               acc[f][2] * rd, acc[f][3] * rd);
        op[f * 4 + quad] = v;                  // o base = f*16 + quad*4
    }
}

extern "C" void kernel_launch(void* const* d_in, const int* in_sizes, int n_in,
                              void* d_out, int out_size, void* d_ws, size_t ws_size,
                              hipStream_t stream) {
    const float* h   = (const float*)d_in[0];  // (1,4096,128) f32
    const int*   adj = (const int*)d_in[1];    // (4096,4096) i32
    const float* W   = (const float*)d_in[2];  // (128,512) f32
    const float* aW  = (const float*)d_in[3];  // (8,128,1) f32
    float* out = (float*)d_out;                // (1,8,4096,64) f32

    // ws layout (total ~4.26 MB; small exp-feeding buffers FIRST):
    //   src  @ 0        (128 KB)
    //   tgt  @ 128 KB   (128 KB)
    //   tmax @ 256 KB   (32 B)
    //   htT  @ 260 KB   (4 MB, bf16)
    // ht itself (f32) lives in d_out (same size); k_attn overwrites it last.
    char* ws = (char*)d_ws;
    float* src  = (float*)(ws);
    float* tgt  = (float*)(ws + 131072);
    float* tmax = (float*)(ws + 262144);
    unsigned short* htT = (unsigned short*)(ws + 266240);
    float* ht = out;

    hipLaunchKernelGGL(k_linear,    dim3(512),  dim3(256), 0, stream, h, W, ht);
    hipLaunchKernelGGL(k_srctgt,    dim3(8192), dim3(256), 0, stream, ht, aW, src, tgt);
    hipLaunchKernelGGL(k_tgtmax,    dim3(8),    dim3(256), 0, stream, tgt, tmax);
    hipLaunchKernelGGL(k_transpose, dim3(512),  dim3(256), 0, stream, ht, htT);
    hipLaunchKernelGGL(k_attn,      dim3(256),  dim3(512), 0, stream, adj, htT, src, tgt, tmax, out);
}

// Round 4
// 227.776 us; speedup vs baseline: 1.4576x; 1.4576x over previous
//
#include <hip/hip_runtime.h>
#include <stdint.h>

#define HT_STRIDE 262144   // 4096*64 elements per head

typedef __attribute__((ext_vector_type(8))) short bf16x8;
typedef __attribute__((ext_vector_type(4))) float f32x4;

__device__ __forceinline__ unsigned short f2bf(float f) {
    unsigned int u = __float_as_uint(f);
    u += 0x7FFFu + ((u >> 16) & 1u);
    return (unsigned short)(u >> 16);
}

// ---------------------------------------------------------------------------
// Kernel A: ht = h(4096x128) @ W(128x512), f32 in, f32 out, into d_out.
// ---------------------------------------------------------------------------
__global__ void __launch_bounds__(256) k_linear(const float* __restrict__ h,
                                                const float* __restrict__ W,
                                                float* __restrict__ ht) {
    __shared__ float hs[8][128];
    const int t = threadIdx.x;
    const int n0 = blockIdx.x * 8;
    {
        float4 v = ((const float4*)(h + n0 * 128))[t];
        int e = t * 4;
        int r = e >> 7, f = e & 127;
        hs[r][f + 0] = v.x; hs[r][f + 1] = v.y;
        hs[r][f + 2] = v.z; hs[r][f + 3] = v.w;
    }
    __syncthreads();
    float acc0[8], acc1[8];
    #pragma unroll
    for (int r = 0; r < 8; ++r) { acc0[r] = 0.f; acc1[r] = 0.f; }
    const float2* Wf = (const float2*)W;
    for (int f = 0; f < 128; ++f) {
        float2 wp = Wf[f * 256 + t];
        #pragma unroll
        for (int r = 0; r < 8; ++r) {
            float hv = hs[r][f];
            acc0[r] = fmaf(hv, wp.x, acc0[r]);
            acc1[r] = fmaf(hv, wp.y, acc1[r]);
        }
    }
    float2* ob = (float2*)ht;
    #pragma unroll
    for (int r = 0; r < 8; ++r) {
        ob[(n0 + r) * 256 + t] = make_float2(acc0[r], acc1[r]);
    }
}

// ---------------------------------------------------------------------------
// Kernel A2: htT2[hd][m>>5][o][m&31] = bf16(ht[hd][m][o])   (k-tiled layout:
// one (hd, 32-k-chunk) tile = 64 o x 32 k = 4 KB contiguous -> k_attn A-frag
// loads are one fully-coalesced 1 KB segment per MFMA).
// ---------------------------------------------------------------------------
__global__ void __launch_bounds__(256) k_transpose(const float* __restrict__ ht,
                                                   unsigned short* __restrict__ htT2) {
    __shared__ unsigned short tile[64][65];   // [m_local][o]
    const int t = threadIdx.x;
    const int hd = blockIdx.x >> 6;
    const int m0 = (blockIdx.x & 63) * 64;
    const float* s = ht + hd * HT_STRIDE + m0 * 64;
    #pragma unroll
    for (int i = 0; i < 16; ++i) {
        int idx = t + 256 * i;                // m_local*64 + o
        tile[idx >> 6][idx & 63] = f2bf(s[idx]);
    }
    __syncthreads();
    unsigned short* d = htT2 + hd * HT_STRIDE + (m0 >> 5) * 2048;
    #pragma unroll
    for (int i = 0; i < 16; ++i) {
        int idx = t + 256 * i;                // o*64 + mi
        int o = idx >> 6, mi = idx & 63;
        d[(mi >> 5) * 2048 + o * 32 + (mi & 31)] = tile[mi][o];
    }
}

// ---------------------------------------------------------------------------
// Kernel B: src/tgt projections. One wave per (head, node).
// ---------------------------------------------------------------------------
__global__ void __launch_bounds__(256) k_srctgt(const float* __restrict__ ht,
                                                const float* __restrict__ aW,
                                                float* __restrict__ src,
                                                float* __restrict__ tgt) {
    const int t = threadIdx.x;
    const int p = blockIdx.x * 4 + (t >> 6);
    const int lane = t & 63;
    const int hd = p >> 12;
    float hv = ht[p * 64 + lane];
    float a1 = aW[hd * 128 + lane];
    float a2 = aW[hd * 128 + 64 + lane];
    float s = hv * a1, g = hv * a2;
    #pragma unroll
    for (int off = 32; off > 0; off >>= 1) {
        s += __shfl_down(s, off, 64);
        g += __shfl_down(g, off, 64);
    }
    if (lane == 0) { src[p] = s; tgt[p] = g; }
}

// ---------------------------------------------------------------------------
// Kernel C: tmax[hd] = max_m tgt[hd][m]
// ---------------------------------------------------------------------------
__global__ void __launch_bounds__(256) k_tgtmax(const float* __restrict__ tgt,
                                                float* __restrict__ tmax) {
    __shared__ float red[256];
    const int t = threadIdx.x;
    const int hd = blockIdx.x;
    float m = -1e30f;
    for (int i = t; i < 4096; i += 256) m = fmaxf(m, tgt[hd * 4096 + i]);
    red[t] = m;
    __syncthreads();
    for (int s2 = 128; s2 > 0; s2 >>= 1) {
        if (t < s2) red[t] = fmaxf(red[t], red[t + s2]);
        __syncthreads();
    }
    if (t == 0) tmax[hd] = red[0];
}

// ---------------------------------------------------------------------------
// Kernel D v2: fused GAT attention.
// block = 1024 thr = 16 waves = 8 heads x 2 k-halves over a 16-row stripe.
//  Phase 1: build 16x4096-bit adjacency mask in LDS (coalesced + __ballot).
//  Phase 2: per wave, 64 pipelined c-iters (32 k each): 1 ds_read bitword +
//           2 float4 tgt + 4 coalesced uint4 A-frags (k-tiled htT2), 8 exp,
//           4 MFMA. Explicit next-iter register prefetch.
//  Phase 3: LDS combine of the two k-halves, denominator, f32 store.
// ---------------------------------------------------------------------------
__global__ void __launch_bounds__(1024) k_attn(const int* __restrict__ adj,
                                               const unsigned short* __restrict__ htT2,
                                               const float* __restrict__ src,
                                               const float* __restrict__ tgt,
                                               const float* __restrict__ tmax,
                                               float* __restrict__ out) {
    __shared__ unsigned int bm[16 * 129];     // 16 rows x 128 words, +1 pad
    __shared__ float comb[8][64][17];         // odd-wave acc(16) + pd(1)

    const int t = threadIdx.x;
    const int wave = t >> 6;                  // 0..15
    const int lane = t & 63;
    const int head = wave >> 1;
    const int khalf = wave & 1;
    const int li = lane & 15;
    const int quad = lane >> 4;
    const int i0 = blockIdx.x * 16;

    // ---- Phase 1: adjacency bitmask (wave w builds row w) ----
    {
        const int* arow = adj + (i0 + wave) * 4096;
        #pragma unroll 4
        for (int s = 0; s < 64; ++s) {
            int v = arow[s * 64 + lane];
            unsigned long long m = __ballot(v > 0);
            if (lane < 2) bm[wave * 129 + 2 * s + lane] = (unsigned int)(m >> (lane * 32));
        }
    }
    __syncthreads();

    // ---- Phase 2: main loop over this wave's k-half ----
    const float sv = src[head * 4096 + i0 + li];
    const float tm0 = sv + tmax[head];
    const float mi = fmaxf(tm0, 0.2f * tm0);  // lrelu(src+max tgt) >= row max

    f32x4 acc[4];
    #pragma unroll
    for (int f = 0; f < 4; ++f) acc[f] = (f32x4){0.f, 0.f, 0.f, 0.f};
    float pd = 0.f;

    const int cbase = khalf * 64;
    const float4* tgtp = (const float4*)(tgt + head * 4096);
    const uint4*  ap   = (const uint4*)(htT2 + head * HT_STRIDE);
    const unsigned int* bmr = bm + li * 129;

    // prefetch iter 0
    unsigned int word = bmr[cbase];
    int kb = cbase * 32 + quad * 8;
    float4 tg0 = tgtp[(kb >> 2) + 0];
    float4 tg1 = tgtp[(kb >> 2) + 1];
    uint4 av[4];
    #pragma unroll
    for (int f = 0; f < 4; ++f) av[f] = ap[cbase * 256 + (f * 16 + li) * 4 + quad];

    for (int c = 0; c < 64; ++c) {
        // issue next-iter loads (c=63 harmlessly reloads c=63's data)
        const int cn = cbase + ((c + 1) & 63);
        unsigned int nword = bmr[cn];
        const int nkb = cn * 32 + quad * 8;
        float4 ntg0 = tgtp[(nkb >> 2) + 0];
        float4 ntg1 = tgtp[(nkb >> 2) + 1];
        uint4 nav[4];
        #pragma unroll
        for (int f = 0; f < 4; ++f) nav[f] = ap[cn * 256 + (f * 16 + li) * 4 + quad];

        // compute current iter
        const float tt[8] = {tg0.x, tg0.y, tg0.z, tg0.w, tg1.x, tg1.y, tg1.z, tg1.w};
        bf16x8 bfrag;
        #pragma unroll
        for (int j = 0; j < 8; ++j) {
            float e = sv + tt[j];
            e = fmaxf(e, 0.2f * e);
            float wv = ((word >> (quad * 8 + j)) & 1u) ? __expf(e - mi) : 0.f;
            pd += wv;
            bfrag[j] = (short)f2bf(wv);
        }
        #pragma unroll
        for (int f = 0; f < 4; ++f) {
            bf16x8 afrag = __builtin_bit_cast(bf16x8, av[f]);
            acc[f] = __builtin_amdgcn_mfma_f32_16x16x32_bf16(afrag, bfrag, acc[f], 0, 0, 0);
        }

        word = nword; tg0 = ntg0; tg1 = ntg1;
        #pragma unroll
        for (int f = 0; f < 4; ++f) av[f] = nav[f];
    }

    // ---- Phase 3: combine k-halves, denominator, store ----
    if (khalf == 1) {
        #pragma unroll
        for (int f = 0; f < 4; ++f) {
            #pragma unroll
            for (int r = 0; r < 4; ++r) comb[head][lane][f * 4 + r] = acc[f][r];
        }
        comb[head][lane][16] = pd;
    }
    __syncthreads();
    if (khalf == 0) {
        #pragma unroll
        for (int f = 0; f < 4; ++f) {
            #pragma unroll
            for (int r = 0; r < 4; ++r) acc[f][r] += comb[head][lane][f * 4 + r];
        }
        pd += comb[head][lane][16];
        pd += __shfl_xor(pd, 16, 64);
        pd += __shfl_xor(pd, 32, 64);
        const float rd = 1.0f / pd;

        float4* op = (float4*)(out + head * HT_STRIDE + (i0 + li) * 64);
        #pragma unroll
        for (int f = 0; f < 4; ++f) {
            float4 v = make_float4(acc[f][0] * rd, acc[f][1] * rd,
                                   acc[f][2] * rd, acc[f][3] * rd);
            op[f * 4 + quad] = v;   // o base = f*16 + quad*4
        }
    }
}

extern "C" void kernel_launch(void* const* d_in, const int* in_sizes, int n_in,
                              void* d_out, int out_size, void* d_ws, size_t ws_size,
                              hipStream_t stream) {
    const float* h   = (const float*)d_in[0];  // (1,4096,128) f32
    const int*   adj = (const int*)d_in[1];    // (4096,4096) i32
    const float* W   = (const float*)d_in[2];  // (128,512) f32
    const float* aW  = (const float*)d_in[3];  // (8,128,1) f32
    float* out = (float*)d_out;                // (1,8,4096,64) f32

    // ws layout (~4.26 MB, proven safe): src | tgt | tmax | htT2(bf16, k-tiled)
    char* ws = (char*)d_ws;
    float* src  = (float*)(ws);
    float* tgt  = (float*)(ws + 131072);
    float* tmax = (float*)(ws + 262144);
    unsigned short* htT2 = (unsigned short*)(ws + 266240);
    float* ht = out;   // ht (f32) lives in d_out; k_attn overwrites it last

    hipLaunchKernelGGL(k_linear,    dim3(512),  dim3(256),  0, stream, h, W, ht);
    hipLaunchKernelGGL(k_srctgt,    dim3(8192), dim3(256),  0, stream, ht, aW, src, tgt);
    hipLaunchKernelGGL(k_tgtmax,    dim3(8),    dim3(256),  0, stream, tgt, tmax);
    hipLaunchKernelGGL(k_transpose, dim3(512),  dim3(256),  0, stream, ht, htT2);
    hipLaunchKernelGGL(k_attn,      dim3(256),  dim3(1024), 0, stream, adj, htT2, src, tgt, tmax, out);
}